// Round 6
// baseline (365.704 us; speedup 1.0000x reference)
//
#include <hip/hip_runtime.h>
#include <stdint.h>

#define B_ROWS 8192
#define DH     1024
#define KTOT   2048   // D_IN + D_H
#define BM     256    // gatecol tile
#define BN     256    // batch tile
#define BK     64
#define NT     (KTOT / BK)   // 32 K-tiles

using short8 = __attribute__((ext_vector_type(8))) short;  // 8 bf16 (4 VGPRs)
using f32x4  = __attribute__((ext_vector_type(4))) float;  // MFMA accumulator

// f32 -> bf16 round-to-nearest-even
__device__ __forceinline__ short bfr(float f) {
    uint32_t u = __float_as_uint(f);
    u = (u + 0x7FFFu + ((u >> 16) & 1u)) >> 16;
    return (short)u;
}

__device__ __forceinline__ float sigm(float x) {
    x = fminf(fmaxf(x, -20.f), 20.f);
    return 1.f / (1.f + __expf(-x));
}
__device__ __forceinline__ float tanh_(float x) {
    x = fminf(fmaxf(x, -10.f), 10.f);
    float e = __expf(2.f * x);
    return (e - 1.f) / (e + 1.f);
}

// async global->LDS, 16B per lane (HW: wave-uniform LDS base + lane*16)
__device__ __forceinline__ void gl16(const void* g, void* l) {
    __builtin_amdgcn_global_load_lds(
        (const __attribute__((address_space(1))) uint32_t*)(uintptr_t)g,
        (__attribute__((address_space(3))) uint32_t*)(uint32_t)(uintptr_t)l,
        16, 0, 0);
}

// A[8192][2048] bf16 = [x | h]   (batch-major, K contiguous)
__global__ __launch_bounds__(256) void build_A(const float* __restrict__ x,
                                               const float* __restrict__ h,
                                               short* __restrict__ A) {
    int t   = blockIdx.x * 256 + threadIdx.x;
    int row = t >> 8;
    int col = (t & 255) * 8;
    const float* src = (col < 1024) ? (x + (size_t)row * 1024 + col)
                                    : (h + (size_t)row * 1024 + (col - 1024));
    float4 f0 = ((const float4*)src)[0];
    float4 f1 = ((const float4*)src)[1];
    short8 o;
    o[0] = bfr(f0.x); o[1] = bfr(f0.y); o[2] = bfr(f0.z); o[3] = bfr(f0.w);
    o[4] = bfr(f1.x); o[5] = bfr(f1.y); o[6] = bfr(f1.z); o[7] = bfr(f1.w);
    *(short8*)(A + (size_t)row * KTOT + col) = o;
}

// Wrow[4096][2048] bf16, GATE-INTERLEAVED rows: row r = 4*hcol + gate,
// gate order {i,f,o,c}:  Wrow[r] = [Wg[hcol] | Ug[hcol]]
__global__ __launch_bounds__(256) void build_W(
        const float* __restrict__ Wi, const float* __restrict__ Ui,
        const float* __restrict__ Wf, const float* __restrict__ Uf,
        const float* __restrict__ Wo, const float* __restrict__ Uo,
        const float* __restrict__ Wc, const float* __restrict__ Uc,
        short* __restrict__ Wrow) {
    int row  = blockIdx.x;
    int col  = threadIdx.x * 8;
    int n    = row >> 2;
    int gate = row & 3;
    const float* Wg = (gate == 0) ? Wi : (gate == 1) ? Wf : (gate == 2) ? Wo : Wc;
    const float* Ug = (gate == 0) ? Ui : (gate == 1) ? Uf : (gate == 2) ? Uo : Uc;
    const float* src = (col < 1024) ? (Wg + (size_t)n * 1024 + col)
                                    : (Ug + (size_t)n * 1024 + (col - 1024));
    float4 f0 = ((const float4*)src)[0];
    float4 f1 = ((const float4*)src)[1];
    short8 o;
    o[0] = bfr(f0.x); o[1] = bfr(f0.y); o[2] = bfr(f0.z); o[3] = bfr(f0.w);
    o[4] = bfr(f1.x); o[5] = bfr(f1.y); o[6] = bfr(f1.z); o[7] = bfr(f1.w);
    *(short8*)(Wrow + (size_t)row * KTOT + col) = o;
}

// gatesT = Wrow (M=4096) x A^T (N=8192), K=2048. 256x256 tile, 8 waves
// (2M x 4N), per-wave 128x64, BK=64. Phase-interleaved schedule:
//   LDS = 2 dbuf x [Wkk0|Wkk1|Akk0|Akk1] quarters (16 KB each) = 128 KiB.
//   Per tile: 2 barrier-intervals (kk=0, kk=1). Interval opens with
//   s_waitcnt vmcnt(4)+s_barrier, then stages the NEXT tile's 2 quarters
//   for the same kk into the idle dbuf (4 gl16), then 2 phases of
//   {ds_read frags, setprio(1), 16 MFMA, setprio(0)}.
//   Per-wave vmcnt ledger at each interval barrier: outstanding = 8
//   (this tile's 4 quarters staged last tile + none newer); oldest 4 are
//   exactly this interval's quarters -> vmcnt(4). Last tile's kk=1
//   interval: outstanding = 4, all needed -> vmcnt(0) (loop exit only).
//   WAR safety: barrier skew <= 1 interval; staged quarters are disjoint
//   from any quarter readable by a wave one interval behind.
// Zero-conflict LDS: chunk ^= (row>>1)&3 XOR swizzle applied on the
// pre-swizzled global source (linear gl16 dest, rule #21) and on ds_read.
__global__ __launch_bounds__(512, 2) void lstm_main(
        const short* __restrict__ Amat, const short* __restrict__ Wrow,
        const float* __restrict__ bi, const float* __restrict__ bff,
        const float* __restrict__ bo, const float* __restrict__ bc,
        const float* __restrict__ cin, float* __restrict__ out) {
    __shared__ __align__(16) short lds[65536];   // 128 KiB

    const int tid  = threadIdx.x;
    const int lane = tid & 63;
    const int wid  = tid >> 6;
    const int wr   = wid >> 2;          // 0..1  (M half)
    const int wc   = wid & 3;           // 0..3  (N quarter)
    const int l15  = lane & 15, l16 = lane >> 4;

    // XCD swizzle (512 % 8 == 0), mtile-major: per-XCD W panel ~2 MB (L2-fit)
    const int bid   = blockIdx.x;
    const int swzb  = (bid & 7) * 64 + (bid >> 3);
    const int mtile = swzb >> 5;        // 0..15
    const int ntile = swzb & 31;        // 0..31
    const int m0 = mtile * BM;
    const int n0 = ntile * BN;

    // ---- staging addresses (global pre-swizzled, LDS linear) ----
    // thread covers quarter-linear bytes tid*16 (+8192 for j=1):
    // row = tid>>2 (+128), chunk = tid&3, swizzled chunk = c ^ ((row>>1)&3)
    const int sr = tid >> 2;                            // 0..127
    const int sc = (tid & 3) ^ ((tid >> 3) & 3);        // (r>>1)&3 == (tid>>3)&3
    const short* pw0 = Wrow + (size_t)(m0 + sr)       * KTOT + sc * 8;
    const short* pw1 = Wrow + (size_t)(m0 + sr + 128) * KTOT + sc * 8;
    const short* pa0 = Amat + (size_t)(n0 + sr)       * KTOT + sc * 8;
    const short* pa1 = Amat + (size_t)(n0 + sr + 128) * KTOT + sc * 8;

    // LDS quarter bases (shorts): W kk -> kk*8192 ; A kk -> 16384 + kk*8192
    auto stageW = [&](int buf, int kk, int tt) {
        short* d = lds + buf * 32768 + kk * 8192 + tid * 8;
        gl16(pw0 + tt * BK + kk * 32, d);
        gl16(pw1 + tt * BK + kk * 32, d + 4096);
    };
    auto stageA = [&](int buf, int kk, int tt) {
        short* d = lds + buf * 32768 + 16384 + kk * 8192 + tid * 8;
        gl16(pa0 + tt * BK + kk * 32, d);
        gl16(pa1 + tt * BK + kk * 32, d + 4096);
    };

    // ---- fragment LDS offsets (shorts), same XOR on the read side ----
    const int swz8  = (l16 ^ ((l15 >> 1) & 3)) * 8;
    const int wbase = (wr * 128 + l15) * 32 + swz8;          // + buf*32768 + kk*8192 + (mq*64+mi*16)*32
    const int abase = 16384 + (wc * 64 + l15) * 32 + swz8;   // + buf*32768 + kk*8192 + ni*512

    f32x4 acc[8][4];
    #pragma unroll
    for (int a = 0; a < 8; ++a)
        #pragma unroll
        for (int ni = 0; ni < 4; ++ni)
            acc[a][ni] = f32x4{0.f, 0.f, 0.f, 0.f};

    // prologue: stage tile 0 (kk0 pair first, then kk1 pair)
    stageW(0, 0, 0); stageA(0, 0, 0);
    stageW(0, 1, 0); stageA(0, 1, 0);

    auto tile_body = [&](int t, int buf) {
        const int bufn = buf ^ 1;
        const short* Lb = lds + buf * 32768;
        const bool more = (t + 1 < NT);

        // ===== interval A : kk = 0 =====
        asm volatile("s_waitcnt vmcnt(4)\n\ts_barrier" ::: "memory");
        if (more) { stageW(bufn, 0, t + 1); stageA(bufn, 0, t + 1); }

        short8 wf[4], af[4];
        #pragma unroll
        for (int mi = 0; mi < 4; ++mi)
            wf[mi] = *(const short8*)(Lb + wbase + mi * 512);
        #pragma unroll
        for (int ni = 0; ni < 4; ++ni)
            af[ni] = *(const short8*)(Lb + abase + ni * 512);
        __builtin_amdgcn_s_setprio(1);
        #pragma unroll
        for (int mi = 0; mi < 4; ++mi)
            #pragma unroll
            for (int ni = 0; ni < 4; ++ni)
                acc[mi][ni] = __builtin_amdgcn_mfma_f32_16x16x32_bf16(
                    wf[mi], af[ni], acc[mi][ni], 0, 0, 0);
        __builtin_amdgcn_s_setprio(0);

        short8 wg[4];
        #pragma unroll
        for (int mi = 0; mi < 4; ++mi)
            wg[mi] = *(const short8*)(Lb + wbase + (64 * 32) + mi * 512);
        __builtin_amdgcn_s_setprio(1);
        #pragma unroll
        for (int mi = 0; mi < 4; ++mi)
            #pragma unroll
            for (int ni = 0; ni < 4; ++ni)
                acc[4 + mi][ni] = __builtin_amdgcn_mfma_f32_16x16x32_bf16(
                    wg[mi], af[ni], acc[4 + mi][ni], 0, 0, 0);
        __builtin_amdgcn_s_setprio(0);

        // ===== interval B : kk = 1 =====
        if (more) {
            asm volatile("s_waitcnt vmcnt(4)\n\ts_barrier" ::: "memory");
            stageW(bufn, 1, t + 1); stageA(bufn, 1, t + 1);
        } else {
            asm volatile("s_waitcnt vmcnt(0)\n\ts_barrier" ::: "memory");
        }

        short8 wf1[4], af1[4];
        #pragma unroll
        for (int mi = 0; mi < 4; ++mi)
            wf1[mi] = *(const short8*)(Lb + 8192 + wbase + mi * 512);
        #pragma unroll
        for (int ni = 0; ni < 4; ++ni)
            af1[ni] = *(const short8*)(Lb + 8192 + abase + ni * 512);
        __builtin_amdgcn_s_setprio(1);
        #pragma unroll
        for (int mi = 0; mi < 4; ++mi)
            #pragma unroll
            for (int ni = 0; ni < 4; ++ni)
                acc[mi][ni] = __builtin_amdgcn_mfma_f32_16x16x32_bf16(
                    wf1[mi], af1[ni], acc[mi][ni], 0, 0, 0);
        __builtin_amdgcn_s_setprio(0);

        short8 wg1[4];
        #pragma unroll
        for (int mi = 0; mi < 4; ++mi)
            wg1[mi] = *(const short8*)(Lb + 8192 + wbase + (64 * 32) + mi * 512);
        __builtin_amdgcn_s_setprio(1);
        #pragma unroll
        for (int mi = 0; mi < 4; ++mi)
            #pragma unroll
            for (int ni = 0; ni < 4; ++ni)
                acc[4 + mi][ni] = __builtin_amdgcn_mfma_f32_16x16x32_bf16(
                    wg1[mi], af1[ni], acc[4 + mi][ni], 0, 0, 0);
        __builtin_amdgcn_s_setprio(0);
    };

    for (int it = 0; it < NT / 2; ++it) {
        tile_body(2 * it, 0);
        tile_body(2 * it + 1, 1);
    }

    // epilogue: reg r of acc[a] = gate r of (hcol, batchrow); all lane-local
    const int hbase = (m0 >> 2) + wr * 32;
    #pragma unroll
    for (int a = 0; a < 8; ++a) {
        const int hcol = hbase + (a >> 2) * 16 + (a & 3) * 4 + l16;
        const float bvi = bi[hcol];
        const float bvf = bff[hcol];
        const float bvo = bo[hcol];
        const float bvc = bc[hcol];
        #pragma unroll
        for (int ni = 0; ni < 4; ++ni) {
            const size_t brow = (size_t)(n0 + wc * 64 + ni * 16 + l15);
            const float cv = cin[brow * DH + hcol];
            const float gi = acc[a][ni][0] + bvi;
            const float gf = acc[a][ni][1] + bvf;
            const float go = acc[a][ni][2] + bvo;
            const float gc = acc[a][ni][3] + bvc;
            const float nc = sigm(gf) * cv + sigm(gi) * tanh_(gc);
            const float nh = sigm(go) * tanh_(nc);
            out[brow * DH + hcol] = nh;
            out[(size_t)B_ROWS * DH + brow * DH + hcol] = nc;
        }
    }
}

extern "C" void kernel_launch(void* const* d_in, const int* in_sizes, int n_in,
                              void* d_out, int out_size, void* d_ws, size_t ws_size,
                              hipStream_t stream) {
    (void)in_sizes; (void)n_in; (void)out_size; (void)ws_size;
    const float* x  = (const float*)d_in[0];
    const float* h  = (const float*)d_in[1];
    const float* c  = (const float*)d_in[2];
    const float* Wi = (const float*)d_in[3];
    const float* bi = (const float*)d_in[4];
    const float* Ui = (const float*)d_in[5];
    const float* Wf = (const float*)d_in[6];
    const float* bf = (const float*)d_in[7];
    const float* Uf = (const float*)d_in[8];
    const float* Wo = (const float*)d_in[9];
    const float* bo = (const float*)d_in[10];
    const float* Uo = (const float*)d_in[11];
    const float* Wc = (const float*)d_in[12];
    const float* bc = (const float*)d_in[13];
    const float* Uc = (const float*)d_in[14];
    float* out = (float*)d_out;

    short* A    = (short*)d_ws;                              // 32 MiB
    short* Wrow = A + (size_t)B_ROWS * KTOT;                 // +16 MiB

    hipLaunchKernelGGL(build_A, dim3(8192), dim3(256), 0, stream, x, h, A);
    hipLaunchKernelGGL(build_W, dim3(4096), dim3(256), 0, stream,
                       Wi, Ui, Wf, Uf, Wo, Uo, Wc, Uc, Wrow);
    hipLaunchKernelGGL(lstm_main, dim3(512), dim3(512), 0, stream,
                       A, Wrow, bi, bf, bo, bc, c, out);
}